// Round 11
// baseline (211.266 us; speedup 1.0000x reference)
//
#include <hip/hip_runtime.h>
#include <hip/hip_fp16.h>
#include <math.h>

#define BB 16
#define NN 96
#define NE 256
#define FF (BB*NN)      // 1536
#define ATOM 128
#define EDIM 16
#define HID 128
#define LAT 128
#define RBFN 16
#define CUTOFF 5.0f
#define ZEMB 32
#define E_ATT 1024
#define M0I 64
#define M1I 32
#define M0O 32
#define M1O 16
#define NODE_DIM 160
#define OUT_DIM 80
#define INVD 48
#define WNUM 4608

// ---- K1 block layout ----
#define K1_TP 192                   // [0,192)    fused GEMM+TP (wave-local contraction)
#define K1_EDGE_AT 192              // [192,448)  4 edges/block: features + k-MLP
#define K1_Q_AT 448                 // [448,960)  8 q-rows/block
#define K1_GATE_AT 960              // [960,976)
#define K1_PREP_AT 976              // [976]
#define K1_BLKS 977

typedef _Float16 half8_t __attribute__((ext_vector_type(8)));
typedef float float4v __attribute__((ext_vector_type(4)));

__device__ __forceinline__ float silu_f(float x) { return x / (1.0f + expf(-x)); }

// =======================================================================
// K1: TP(GEMM+contract) + edge k-MLP + q-MLP + gates + prep
// TP blocks: wave-local contraction -> 4 barriers instead of 27.
// =======================================================================
__global__ __launch_bounds__(256) void k1(
    const float* __restrict__ h, const float* __restrict__ h_full,
    const float* __restrict__ z_emb, const int* __restrict__ z,
    const int* __restrict__ absorber, const float* __restrict__ e_feat,
    const int* __restrict__ att_dst, const float* __restrict__ att_dist,
    const float* __restrict__ att_vec,
    const float* __restrict__ rw1, const float* __restrict__ rb1,
    const float* __restrict__ rw2, const float* __restrict__ rb2,
    const float* __restrict__ kw1, const float* __restrict__ kb1,
    const float* __restrict__ kw2, const float* __restrict__ kb2,
    const float* __restrict__ kw3, const float* __restrict__ kb3,
    const float* __restrict__ qw1, const float* __restrict__ qb1,
    const float* __restrict__ qw2, const float* __restrict__ qb2,
    const float* __restrict__ qw3, const float* __restrict__ qb3,
    const float* __restrict__ ew1, const float* __restrict__ eb1,
    const float* __restrict__ ew2, const float* __restrict__ eb2,
    float* __restrict__ kmatw, float* __restrict__ qmat,
    float* __restrict__ gexp, float* __restrict__ virr,
    int* __restrict__ inv)
{
    __shared__ __align__(16) char smemraw[37760];
    float* smem = (float*)smemraw;
    int blk = blockIdx.x;
    int t = threadIdx.x;

    if (blk < K1_TP) {
        // cls: 0 -> out0[:,0:16) (even SEG0/SEG3 tiles); 1 -> out0[:,16:32) (odd);
        // 2 -> out1 (SEG1+SEG2). tile -> edges [tile*16, tile*16+16).
        float*  winf  = (float*)smemraw;                 // [16][52] floats (prologue only)
        float*  fbase = (float*)smemraw + 1088;          // @4352B
        float* x0f  = fbase;                             // [16][65] (pad: conflict-free bcast)
        float* x1f  = fbase + 1040;                      // [16][97]
        float* xyf  = fbase + 2592;                      // [16][33]
        float* y1f  = fbase + 3120;                      // [16][4]
        float* envf = fbase + 3184;                      // [16]
        float* dS   = fbase + 3200;                      // [16]
        int*   fI   = (int*)(fbase + 3216);              // [16]
        _Float16* hS = (_Float16*)(smemraw + 17280);     // [16][128] halves
        float* pS   = (float*)(smemraw + 21376);         // [4 wv][4 var][16][16] = 16 KB

        int cls  = blk % 3;
        int tile = blk / 3;
        int e0t = tile * 16;
        if (t < 16) {
            int e = e0t + t;
            int f = att_dst[e];
            fI[t] = f;
            float d = att_dist[e];
            dS[t] = d;
            envf[t] = (d < CUTOFF) ? 0.5f*(cosf(3.14159265358979323846f*d/CUTOFF) + 1.0f) : 0.0f;
            float vx = att_vec[3*e], vy = att_vec[3*e+1], vz = att_vec[3*e+2];
            float nrm = sqrtf(vx*vx + vy*vy + vz*vz);
            float is = 1.0f / fmaxf(nrm, 1e-8f);
            const float s3 = 1.7320508075688772f;
            y1f[t*4]   = s3*vx*is;
            y1f[t*4+1] = s3*vy*is;
            y1f[t*4+2] = s3*vz*is;
        }
        __syncthreads();
        for (int u = t; u < 16*49; u += 256) {
            int e = u / 49, j = u - 49*(u/49);
            int f = fI[e];
            float v;
            if (j < ZEMB) v = z_emb[z[f]*ZEMB + j];
            else if (j == ZEMB) { int b = f / NN, nn = f - b*NN; v = (absorber[b] == nn) ? 1.0f : 0.0f; }
            else {
                int jr = j - 33;
                const float delta = CUTOFF / (RBFN - 1);
                float diff = dS[e] - jr*delta;
                v = expf(-diff*diff / (2.0f*delta*delta));
            }
            winf[e*52 + j] = v;
        }
        for (int p = 0; p < 10; p++) {
            int idx = t + 256*p;
            int edge = idx / 160, j = idx - 160*edge;
            float v = h_full[fI[edge]*NODE_DIM + j];
            if (j < M0I) x0f[edge*65 + j] = v;
            else         x1f[edge*97 + (j - M0I)] = v;
        }
        __syncthreads();
        for (int p = 0; p < 2; p++) {
            int idx = t + 256*p;
            int edge = idx >> 5, i = idx & 31;
            xyf[edge*33 + i] = x1f[edge*97 + 3*i]*y1f[edge*4]
                             + x1f[edge*97 + 3*i+1]*y1f[edge*4+1]
                             + x1f[edge*97 + 3*i+2]*y1f[edge*4+2];
        }
        // hidden = silu(w_in @ rw1 + rb1): 16 edges x 128 cols, fp16 into hS
        {
            int e = t >> 4;
            const float* wf = winf + e*52;
            #pragma unroll
            for (int p = 0; p < 4; p++) {
                int c2 = 2*((t & 15) + 16*p);
                float2 a0 = *(const float2*)&rb1[c2];
                float2 a1 = make_float2(0.f, 0.f);
                #pragma unroll 8
                for (int i = 0; i < 48; i += 2) {
                    float x0v = wf[i], x1v = wf[i + 1];
                    float2 w0 = *(const float2*)&rw1[i*HID + c2];
                    float2 w1 = *(const float2*)&rw1[(i+1)*HID + c2];
                    a0.x += x0v*w0.x; a0.y += x0v*w0.y;
                    a1.x += x1v*w1.x; a1.y += x1v*w1.y;
                }
                {
                    float x0v = wf[48];
                    float2 w0 = *(const float2*)&rw1[48*HID + c2];
                    a0.x += x0v*w0.x; a0.y += x0v*w0.y;
                }
                *(__half2*)&hS[e*128 + c2] =
                    __floats2half2_rn(silu_f(a0.x + a1.x), silu_f(a0.y + a1.y));
            }
        }
        __syncthreads();

        int wv = t >> 6;
        int lane = t & 63;
        int mrow = lane & 15, quad = lane >> 4;
        half8_t af[4];
        #pragma unroll
        for (int kc = 0; kc < 4; kc++)
            af[kc] = *(const half8_t*)&hS[mrow*128 + quad*8 + kc*32];

        int clsAdd = (cls == 1) ? 1 : 0;
        // wave-local partials: pa=t00/t01, pb=t11/tm0, pc=tm1, pd=tm2 (per r)
        float pa[4] = {0.f,0.f,0.f,0.f}, pb[4] = {0.f,0.f,0.f,0.f};
        float pc[4] = {0.f,0.f,0.f,0.f}, pd[4] = {0.f,0.f,0.f,0.f};

        // wave wv owns j in [wv*24, wv*24+24): 24 independent load->MFMA->FMA chains
        #pragma unroll 2
        for (int jj = 0; jj < 24; jj++) {
            int j = wv*24 + jj;
            int ntg = (cls == 2) ? (128 + j)
                                 : (2*j + clsAdd + ((j >= 64) ? 96 : 0));
            const float* bcol = rw2 + ntg*16 + mrow;
            float4v acc = {0.f, 0.f, 0.f, 0.f};
            #pragma unroll
            for (int kc = 0; kc < 4; kc++) {
                half8_t bfr;
                #pragma unroll
                for (int m = 0; m < 8; m++)
                    bfr[m] = (_Float16)bcol[(quad*8 + kc*32 + m)*WNUM];
                acc = __builtin_amdgcn_mfma_f32_16x16x32_f16(af[kc], bfr, acc, 0, 0, 0);
            }
            float bias = rb2[ntg*16 + mrow];
            // lane holds C[edge=quad*4+r][o=mrow] = acc[r]+bias (fp32, no fp16 round)
            if (cls < 2) {
                if (j < 64) {
                    #pragma unroll
                    for (int r = 0; r < 4; r++)
                        pa[r] += x0f[(quad*4 + r)*65 + j]*(acc[r] + bias);
                } else {
                    #pragma unroll
                    for (int r = 0; r < 4; r++)
                        pb[r] += xyf[(quad*4 + r)*33 + (j - 64)]*(acc[r] + bias);
                }
            } else {
                if (j < 64) {
                    #pragma unroll
                    for (int r = 0; r < 4; r++)
                        pa[r] += x0f[(quad*4 + r)*65 + j]*(acc[r] + bias);
                } else {
                    int i = j - 64;
                    #pragma unroll
                    for (int r = 0; r < 4; r++) {
                        float C = acc[r] + bias;
                        pb[r] += x1f[(quad*4 + r)*97 + 3*i]*C;
                        pc[r] += x1f[(quad*4 + r)*97 + 3*i+1]*C;
                        pd[r] += x1f[(quad*4 + r)*97 + 3*i+2]*C;
                    }
                }
            }
        }
        // cross-wave reduce via LDS partials
        #pragma unroll
        for (int r = 0; r < 4; r++) {
            int edge = quad*4 + r;
            pS[((wv*4 + 0)*16 + edge)*16 + mrow] = pa[r];
            pS[((wv*4 + 1)*16 + edge)*16 + mrow] = pb[r];
            if (cls == 2) {
                pS[((wv*4 + 2)*16 + edge)*16 + mrow] = pc[r];
                pS[((wv*4 + 3)*16 + edge)*16 + mrow] = pd[r];
            }
        }
        __syncthreads();
        {
            int edge = t >> 4, o = t & 15;
            const float alpha = 0.10206207261596575f;  // 1/sqrt(96)
            const float ccf   = 0.5773502691896258f;   // 1/sqrt(3)
            int f = fI[edge];
            float env = envf[edge];
            float s0 = pS[((0*4+0)*16 + edge)*16 + o] + pS[((1*4+0)*16 + edge)*16 + o]
                     + pS[((2*4+0)*16 + edge)*16 + o] + pS[((3*4+0)*16 + edge)*16 + o];
            float s1 = pS[((0*4+1)*16 + edge)*16 + o] + pS[((1*4+1)*16 + edge)*16 + o]
                     + pS[((2*4+1)*16 + edge)*16 + o] + pS[((3*4+1)*16 + edge)*16 + o];
            if (cls < 2) {
                virr[f*OUT_DIM + cls*16 + o] = alpha*(s0 + ccf*s1)*env;
            } else {
                float s2 = pS[((0*4+2)*16 + edge)*16 + o] + pS[((1*4+2)*16 + edge)*16 + o]
                         + pS[((2*4+2)*16 + edge)*16 + o] + pS[((3*4+2)*16 + edge)*16 + o];
                float s3 = pS[((0*4+3)*16 + edge)*16 + o] + pS[((1*4+3)*16 + edge)*16 + o]
                         + pS[((2*4+3)*16 + edge)*16 + o] + pS[((3*4+3)*16 + edge)*16 + o];
                float y0 = y1f[edge*4], y1v = y1f[edge*4+1], y2 = y1f[edge*4+2];
                virr[f*OUT_DIM + M0O + 3*o]     = alpha*ccf*(s0*y0 + s1)*env;
                virr[f*OUT_DIM + M0O + 3*o + 1] = alpha*ccf*(s0*y1v + s2)*env;
                virr[f*OUT_DIM + M0O + 3*o + 2] = alpha*ccf*(s0*y2 + s3)*env;
            }
        }
    } else if (blk < K1_Q_AT) {
        // ---- edge features + k-MLP (proven verbatim) ----
        float (*sin1)[184] = (float(*)[184])smem;
        float (*l1S)[128]  = (float(*)[128])(smem + 736);
        float (*l2S)[128]  = (float(*)[128])(smem + 736 + 512);
        int w = t >> 6;
        int c = t & 63;
        int e = (blk - K1_EDGE_AT)*4 + w;
        int f = att_dst[e];
        int b = f / NN, nn = f - b*NN;
        float d = att_dist[e];
        {
            float2 hv = *(const float2*)&h[f*ATOM + 2*c];
            sin1[w][2*c] = hv.x; sin1[w][2*c + 1] = hv.y;
        }
        if (c < ZEMB) sin1[w][ATOM + c] = z_emb[z[f]*ZEMB + c];
        if (c >= 32 && c < 48) {
            int j = c - 32;
            const float delta = CUTOFF / (RBFN - 1);
            float diff = d - j*delta;
            sin1[w][ATOM + ZEMB + 1 + j] = expf(-diff*diff / (2.0f*delta*delta));
        }
        if (c == 48) sin1[w][ATOM + ZEMB] = (absorber[b] == nn) ? 1.0f : 0.0f;
        __syncthreads();
        int c2 = 2*c;
        {   // k layer 1: 177 -> 128
            float2 a0 = *(const float2*)&kb1[c2];
            float2 a1 = make_float2(0.f, 0.f);
            #pragma unroll 8
            for (int i = 0; i < 176; i += 2) {
                float x0v = sin1[w][i], x1v = sin1[w][i + 1];
                float2 w0 = *(const float2*)&kw1[i*HID + c2];
                float2 w1 = *(const float2*)&kw1[(i+1)*HID + c2];
                a0.x += x0v*w0.x; a0.y += x0v*w0.y;
                a1.x += x1v*w1.x; a1.y += x1v*w1.y;
            }
            {
                float x0v = sin1[w][176];
                float2 w0 = *(const float2*)&kw1[176*HID + c2];
                a0.x += x0v*w0.x; a0.y += x0v*w0.y;
            }
            l1S[w][c2] = silu_f(a0.x + a1.x); l1S[w][c2+1] = silu_f(a0.y + a1.y);
        }
        __syncthreads();
        {   // k layer 2
            float2 a0 = *(const float2*)&kb2[c2];
            float2 a1 = make_float2(0.f, 0.f);
            #pragma unroll 8
            for (int i = 0; i < HID; i += 2) {
                float x0v = l1S[w][i], x1v = l1S[w][i + 1];
                float2 w0 = *(const float2*)&kw2[i*HID + c2];
                float2 w1 = *(const float2*)&kw2[(i+1)*HID + c2];
                a0.x += x0v*w0.x; a0.y += x0v*w0.y;
                a1.x += x1v*w1.x; a1.y += x1v*w1.y;
            }
            l2S[w][c2] = silu_f(a0.x + a1.x); l2S[w][c2+1] = silu_f(a0.y + a1.y);
        }
        __syncthreads();
        {   // k layer 3 -> kmat
            float2 a0 = *(const float2*)&kb3[c2];
            float2 a1 = make_float2(0.f, 0.f);
            #pragma unroll 8
            for (int i = 0; i < HID; i += 2) {
                float x0v = l2S[w][i], x1v = l2S[w][i + 1];
                float2 w0 = *(const float2*)&kw3[i*HID + c2];
                float2 w1 = *(const float2*)&kw3[(i+1)*HID + c2];
                a0.x += x0v*w0.x; a0.y += x0v*w0.y;
                a1.x += x1v*w1.x; a1.y += x1v*w1.y;
            }
            float2 o; o.x = a0.x + a1.x; o.y = a0.y + a1.y;
            *(float2*)&kmatw[f*HID + c2] = o;
        }
    } else if (blk < K1_GATE_AT) {
        // ---- q-MLP (proven verbatim) ----
        float* hA          = smem;
        float (*ef)[16]    = (float(*)[16])(smem + 128);
        float (*part)[128] = (float(*)[128])(smem + 256);
        float* l1S         = smem + 1280;
        float* l2S         = smem + 2304;
        int idx = blk - K1_Q_AT;
        int r0 = idx * 8;
        int b  = r0 >> 8;
        int e8 = r0 & 255;
        if (t < 32) *(float4*)&hA[t*4] = *(const float4*)&h[(b*NN + absorber[b])*ATOM + t*4];
        if (t >= 128 && t < 256) { int e = (t - 128) >> 4, j = t & 15; ef[e][j] = e_feat[(e8 + e)*EDIM + j]; }
        __syncthreads();
        int r = t >> 5, c0 = (t & 31)*4;
        {
            float4 a0 = make_float4(0,0,0,0);
            int k0 = r*16;
            #pragma unroll
            for (int k = 0; k < 16; k++) {
                float hv = hA[k0 + k];
                float4 w0 = *(const float4*)&qw1[(k0 + k)*HID + c0];
                a0.x += hv*w0.x; a0.y += hv*w0.y; a0.z += hv*w0.z; a0.w += hv*w0.w;
            }
            *(float4*)&part[r][c0] = a0;
        }
        __syncthreads();
        {
            float4 s = *(const float4*)&qb1[c0];
            #pragma unroll
            for (int g = 0; g < 8; g++) {
                float4 pg = *(const float4*)&part[g][c0];
                s.x += pg.x; s.y += pg.y; s.z += pg.z; s.w += pg.w;
            }
            #pragma unroll
            for (int j = 0; j < 16; j++) {
                float a = ef[r][j];
                float4 w0 = *(const float4*)&qw1[(ATOM + j)*HID + c0];
                s.x += a*w0.x; s.y += a*w0.y; s.z += a*w0.z; s.w += a*w0.w;
            }
            l1S[r*128 + c0]   = silu_f(s.x); l1S[r*128 + c0+1] = silu_f(s.y);
            l1S[r*128 + c0+2] = silu_f(s.z); l1S[r*128 + c0+3] = silu_f(s.w);
        }
        __syncthreads();
        {
            float4 a0 = *(const float4*)&qb2[c0];
            float4 a1 = make_float4(0,0,0,0);
            #pragma unroll 8
            for (int i = 0; i < HID; i += 2) {
                float x0v = l1S[r*128 + i], x1v = l1S[r*128 + i+1];
                float4 w0 = *(const float4*)&qw2[i*HID + c0];
                float4 w1 = *(const float4*)&qw2[(i+1)*HID + c0];
                a0.x += x0v*w0.x; a0.y += x0v*w0.y; a0.z += x0v*w0.z; a0.w += x0v*w0.w;
                a1.x += x1v*w1.x; a1.y += x1v*w1.y; a1.z += x1v*w1.z; a1.w += x1v*w1.w;
            }
            l2S[r*128 + c0]   = silu_f(a0.x + a1.x); l2S[r*128 + c0+1] = silu_f(a0.y + a1.y);
            l2S[r*128 + c0+2] = silu_f(a0.z + a1.z); l2S[r*128 + c0+3] = silu_f(a0.w + a1.w);
        }
        __syncthreads();
        {
            float4 a0 = *(const float4*)&qb3[c0];
            float4 a1 = make_float4(0,0,0,0);
            #pragma unroll 8
            for (int i = 0; i < HID; i += 2) {
                float x0v = l2S[r*128 + i], x1v = l2S[r*128 + i+1];
                float4 w0 = *(const float4*)&qw3[i*HID + c0];
                float4 w1 = *(const float4*)&qw3[(i+1)*HID + c0];
                a0.x += x0v*w0.x; a0.y += x0v*w0.y; a0.z += x0v*w0.z; a0.w += x0v*w0.w;
                a1.x += x1v*w1.x; a1.y += x1v*w1.y; a1.z += x1v*w1.z; a1.w += x1v*w1.w;
            }
            float4 o;
            o.x = a0.x + a1.x; o.y = a0.y + a1.y; o.z = a0.z + a1.z; o.w = a0.w + a1.w;
            *(float4*)&qmat[(r0 + r)*LAT + c0] = o;
        }
    } else if (blk < K1_PREP_AT) {
        // ---- gates (proven verbatim) ----
        float (*ef)[16]   = (float(*)[16])smem;
        float (*l1g)[128] = (float(*)[128])(smem + 256);
        float (*gg)[48]   = (float(*)[48])(smem + 256 + 2048);
        int e0 = (blk - K1_GATE_AT) * 16;
        { int e = t >> 4, i = t & 15; ef[e][i] = e_feat[(e0 + e)*EDIM + i]; }
        __syncthreads();
        int r = t >> 4, c0 = (t & 15)*8;
        {
            float4 a0 = *(const float4*)&eb1[c0];
            float4 a1 = *(const float4*)&eb1[c0 + 4];
            #pragma unroll
            for (int i = 0; i < EDIM; i++) {
                float a = ef[r][i];
                float4 w0 = *(const float4*)&ew1[i*HID + c0];
                float4 w1 = *(const float4*)&ew1[i*HID + c0 + 4];
                a0.x += a*w0.x; a0.y += a*w0.y; a0.z += a*w0.z; a0.w += a*w0.w;
                a1.x += a*w1.x; a1.y += a*w1.y; a1.z += a*w1.z; a1.w += a*w1.w;
            }
            l1g[r][c0]   = silu_f(a0.x); l1g[r][c0+1] = silu_f(a0.y);
            l1g[r][c0+2] = silu_f(a0.z); l1g[r][c0+3] = silu_f(a0.w);
            l1g[r][c0+4] = silu_f(a1.x); l1g[r][c0+5] = silu_f(a1.y);
            l1g[r][c0+6] = silu_f(a1.z); l1g[r][c0+7] = silu_f(a1.w);
        }
        __syncthreads();
        for (int u = t; u < 16*48; u += 256) {
            int e = u / 48, j = u - 48*(u/48);
            float acc = eb2[j];
            #pragma unroll 4
            for (int i = 0; i < HID; i++) acc += l1g[e][i]*ew2[i*48 + j];
            gg[e][j] = acc;
        }
        __syncthreads();
        for (int u = t; u < 16*80; u += 256) {
            int e = u / 80, cc = u - 80*(u/80);
            gexp[(e0 + e)*OUT_DIM + cc] = (cc < M0O) ? gg[e][cc] : gg[e][M0O + (cc - M0O)/3];
        }
    } else {
        // ---- prep: inv init + scatter ----
        for (int p = 0; p < 6; p++) inv[t + 256*p] = -1;
        __syncthreads();
        for (int p = 0; p < 4; p++) { int e = t + 256*p; inv[att_dst[e]] = e; }
    }
}

// =======================================================================
// K2: in-block scores GEMM + softmax + PV + final MLP (R10-proven)
// =======================================================================
__global__ __launch_bounds__(256) void k_attf(
    const float* __restrict__ qmat, const float* __restrict__ kmat,
    const int* __restrict__ inv,
    const float* __restrict__ virr, const float* __restrict__ gexp,
    const float* __restrict__ ow1, const float* __restrict__ ob1,
    const float* __restrict__ ow2, const float* __restrict__ ob2,
    const float* __restrict__ ow3, const float* __restrict__ ob3,
    float* __restrict__ out)
{
    int b  = blockIdx.x >> 5;
    int e0 = (blockIdx.x & 31) * 8;
    int t = threadIdx.x;
    __shared__ float smem[16448];
    float (*aS)[100]   = (float(*)[100])smem;            // 800
    float (*gS)[84]    = (float(*)[84])(smem + 800);     // 672
    float (*ocS)[84]   = (float(*)[84])(smem + 1472);    // 672
    float* mS          = smem + 2144;                    // 96
    float (*inS)[INVD] = (float(*)[INVD])(smem + 2240);  // 384
    float (*q8)[132]   = (float(*)[132])(smem + 2624);   // 1056 -> 3680
    float* Kt          = smem + 3680;                    // [96][133]=12768 (scores phase)
    float (*l1S)[HID]  = (float(*)[HID])(smem + 3680);   // alias (MLP phase)
    float (*l2S)[HID]  = (float(*)[HID])(smem + 3680 + 1024);

    if (t < 160) {
        int el = t / 20, c4 = t - 20*(t/20);
        *(float4*)&gS[el][c4*4] = *(const float4*)&gexp[(e0 + el)*OUT_DIM + c4*4];
    }
    if (t < NN) mS[t] = ((unsigned)inv[b*NN + t] < E_ATT) ? 1.0f : 0.0f;
    {
        int el = t >> 5, i4 = t & 31;
        *(float4*)&q8[el][i4*4] = *(const float4*)&qmat[(b*NE + e0 + el)*LAT + i4*4];
    }
    // ---- stage ALL 96 K rows once (stride 133 conflict-free) ----
    for (int p = 0; p < 12; p++) {
        int idx = t + 256*p; int n = idx >> 5, i4 = idx & 31;
        *(float4*)&Kt[n*133 + i4*4] = *(const float4*)&kmat[(b*NN + n)*LAT + i4*4];
    }
    __syncthreads();

    // ---- scores: 8 e-rows x 96 n; 3 back-to-back 128-dots per lane ----
    int el = t >> 5, tn = t & 31;
    float sacc0, sacc1, sacc2;
    {
        const float* qp = &q8[el][0];
        const float* kp0 = &Kt[tn*133];
        const float* kp1 = &Kt[(32 + tn)*133];
        const float* kp2 = &Kt[(64 + tn)*133];
        float a00 = 0.f, a01 = 0.f, a10 = 0.f, a11 = 0.f, a20 = 0.f, a21 = 0.f;
        #pragma unroll 16
        for (int i = 0; i < LAT; i += 2) {
            float q0 = qp[i], q1 = qp[i+1];
            a00 += q0*kp0[i]; a01 += q1*kp0[i+1];
            a10 += q0*kp1[i]; a11 += q1*kp1[i+1];
            a20 += q0*kp2[i]; a21 += q1*kp2[i+1];
        }
        sacc0 = a00 + a01; sacc1 = a10 + a11; sacc2 = a20 + a21;
    }

    // ---- masked scores + softmax ----
    {
        const float scale = 0.04419417382415922f;  // (1/HEADS)*HD^-0.5
        int ng = tn;
        float m0 = mS[ng], m1 = mS[ng + 32], m2 = mS[ng + 64];
        float s0 = (m0 != 0.f) ? sacc0*scale : -1e9f;
        float s1 = (m1 != 0.f) ? sacc1*scale : -1e9f;
        float s2 = (m2 != 0.f) ? sacc2*scale : -1e9f;
        float mx = fmaxf(s0, fmaxf(s1, s2));
        #pragma unroll
        for (int off = 1; off < 32; off <<= 1) mx = fmaxf(mx, __shfl_xor(mx, off));
        float e0v = expf(s0 - mx), e1v = expf(s1 - mx), e2v = expf(s2 - mx);
        float sm = e0v + e1v + e2v;
        #pragma unroll
        for (int off = 1; off < 32; off <<= 1) sm += __shfl_xor(sm, off);
        float r = 1.0f / sm;
        float p0 = m0*e0v*r, p1 = m1*e1v*r, p2 = m2*e2v*r;
        float ss = p0 + p1 + p2;
        #pragma unroll
        for (int off = 1; off < 32; off <<= 1) ss += __shfl_xor(ss, off);
        float is = 1.0f / fmaxf(ss, 1e-8f);
        aS[el][ng]      = p0*is;
        aS[el][ng + 32] = p1*is;
        aS[el][ng + 64] = p2*is;
    }
    __syncthreads();

    if (t < 160) {
        int el2 = t / 20, c4 = t - 20*(t/20);
        const float* vp = virr + (long)b*NN*OUT_DIM + c4*4;
        float4 acc = make_float4(0,0,0,0);
        #pragma unroll 8
        for (int n = 0; n < NN; n++) {
            float a = aS[el2][n];
            float4 v = *(const float4*)&vp[n*OUT_DIM];
            acc.x += a*v.x; acc.y += a*v.y; acc.z += a*v.z; acc.w += a*v.w;
        }
        float4 g = *(float4*)&gS[el2][c4*4];
        float4 o; o.x = acc.x*g.x; o.y = acc.y*g.y; o.z = acc.z*g.z; o.w = acc.w*g.w;
        *(float4*)&ocS[el2][c4*4] = o;
    }
    __syncthreads();

    for (int u = t; u < 8*INVD; u += 256) {
        int el2 = u / INVD, j = u - INVD*(u/INVD);
        float val;
        if (j < M0O) val = ocS[el2][j];
        else {
            int o = j - M0O;
            float x = ocS[el2][M0O + 3*o], y = ocS[el2][M0O + 3*o + 1], zz = ocS[el2][M0O + 3*o + 2];
            val = sqrtf(x*x + y*y + zz*zz + 1e-12f);
        }
        inS[el2][j] = val;
    }
    __syncthreads();

    int r = t >> 5, c0 = (t & 31)*4;
    {
        float4 a0 = *(const float4*)&ob1[c0];
        float4 a1 = make_float4(0,0,0,0);
        #pragma unroll 8
        for (int i = 0; i < INVD; i += 2) {
            float x0v = inS[r][i], x1v = inS[r][i+1];
            float4 w0 = *(const float4*)&ow1[i*HID + c0];
            float4 w1 = *(const float4*)&ow1[(i+1)*HID + c0];
            a0.x += x0v*w0.x; a0.y += x0v*w0.y; a0.z += x0v*w0.z; a0.w += x0v*w0.w;
            a1.x += x1v*w1.x; a1.y += x1v*w1.y; a1.z += x1v*w1.z; a1.w += x1v*w1.w;
        }
        l1S[r][c0]   = silu_f(a0.x + a1.x); l1S[r][c0+1] = silu_f(a0.y + a1.y);
        l1S[r][c0+2] = silu_f(a0.z + a1.z); l1S[r][c0+3] = silu_f(a0.w + a1.w);
    }
    __syncthreads();
    {
        float4 a0 = *(const float4*)&ob2[c0];
        float4 a1 = make_float4(0,0,0,0);
        #pragma unroll 8
        for (int i = 0; i < HID; i += 2) {
            float x0v = l1S[r][i], x1v = l1S[r][i+1];
            float4 w0 = *(const float4*)&ow2[i*HID + c0];
            float4 w1 = *(const float4*)&ow2[(i+1)*HID + c0];
            a0.x += x0v*w0.x; a0.y += x0v*w0.y; a0.z += x0v*w0.z; a0.w += x0v*w0.w;
            a1.x += x1v*w1.x; a1.y += x1v*w1.y; a1.z += x1v*w1.z; a1.w += x1v*w1.w;
        }
        l2S[r][c0]   = silu_f(a0.x + a1.x); l2S[r][c0+1] = silu_f(a0.y + a1.y);
        l2S[r][c0+2] = silu_f(a0.z + a1.z); l2S[r][c0+3] = silu_f(a0.w + a1.w);
    }
    __syncthreads();
    {
        float4 a0 = *(const float4*)&ob3[c0];
        float4 a1 = make_float4(0,0,0,0);
        #pragma unroll 8
        for (int i = 0; i < HID; i += 2) {
            float x0v = l2S[r][i], x1v = l2S[r][i+1];
            float4 w0 = *(const float4*)&ow3[i*HID + c0];
            float4 w1 = *(const float4*)&ow3[(i+1)*HID + c0];
            a0.x += x0v*w0.x; a0.y += x0v*w0.y; a0.z += x0v*w0.z; a0.w += x0v*w0.w;
            a1.x += x1v*w1.x; a1.y += x1v*w1.y; a1.z += x1v*w1.z; a1.w += x1v*w1.w;
        }
        float4 o;
        o.x = a0.x + a1.x; o.y = a0.y + a1.y; o.z = a0.z + a1.z; o.w = a0.w + a1.w;
        *(float4*)&out[((b*NE + e0) + r)*LAT + c0] = o;
    }
}

extern "C" void kernel_launch(void* const* d_in, const int* in_sizes, int n_in,
                              void* d_out, int out_size, void* d_ws, size_t ws_size,
                              hipStream_t stream) {
    const float* h        = (const float*)d_in[0];
    const float* h_full   = (const float*)d_in[1];
    const float* e_feat   = (const float*)d_in[2];
    const float* att_dist = (const float*)d_in[3];
    const float* att_vec  = (const float*)d_in[4];
    const float* z_emb    = (const float*)d_in[5];
    const float* rw1 = (const float*)d_in[6];  const float* rb1 = (const float*)d_in[7];
    const float* rw2 = (const float*)d_in[8];  const float* rb2 = (const float*)d_in[9];
    const float* ew1 = (const float*)d_in[10]; const float* eb1 = (const float*)d_in[11];
    const float* ew2 = (const float*)d_in[12]; const float* eb2 = (const float*)d_in[13];
    const float* qw1 = (const float*)d_in[14]; const float* qb1 = (const float*)d_in[15];
    const float* qw2 = (const float*)d_in[16]; const float* qb2 = (const float*)d_in[17];
    const float* qw3 = (const float*)d_in[18]; const float* qb3 = (const float*)d_in[19];
    const float* kw1 = (const float*)d_in[20]; const float* kb1 = (const float*)d_in[21];
    const float* kw2 = (const float*)d_in[22]; const float* kb2 = (const float*)d_in[23];
    const float* kw3 = (const float*)d_in[24]; const float* kb3 = (const float*)d_in[25];
    const float* ow1 = (const float*)d_in[26]; const float* ob1 = (const float*)d_in[27];
    const float* ow2 = (const float*)d_in[28]; const float* ob2 = (const float*)d_in[29];
    const float* ow3 = (const float*)d_in[30]; const float* ob3 = (const float*)d_in[31];
    const int* z        = (const int*)d_in[32];
    const int* absorber = (const int*)d_in[34];
    const int* att_dst  = (const int*)d_in[35];

    float* ws = (float*)d_ws;
    int*   inv     = (int*)ws;                    // 1536
    float* kmat    = ws + 5632;                   // 196608 (1536x128)
    float* qmat    = ws + 202240;                 // 524288 (4096x128)
    float* gexp    = ws + 726528;                 // 20480
    float* virr    = ws + 747008;                 // 122880 (1536x80)

    float* out = (float*)d_out;

    k1<<<K1_BLKS, 256, 0, stream>>>(h, h_full, z_emb, z, absorber, e_feat,
                                    att_dst, att_dist, att_vec,
                                    rw1, rb1, rw2, rb2,
                                    kw1, kb1, kw2, kb2, kw3, kb3,
                                    qw1, qb1, qw2, qb2, qw3, qb3,
                                    ew1, eb1, ew2, eb2,
                                    kmat, qmat, gexp, virr, inv);
    k_attf<<<BB*32, 256, 0, stream>>>(qmat, kmat, inv, virr, gexp,
                                      ow1, ob1, ow2, ob2, ow3, ob3, out);
}